// Round 4
// baseline (1243.956 us; speedup 1.0000x reference)
//
#include <hip/hip_runtime.h>
#include <stdint.h>
#include <math.h>

typedef unsigned short u16;
typedef __attribute__((ext_vector_type(8))) short short8;
typedef __attribute__((ext_vector_type(4))) float f32x4;

__device__ __forceinline__ float bf2f(u16 u){
  union { unsigned int i; float f; } v; v.i = ((unsigned int)u) << 16; return v.f;
}
__device__ __forceinline__ u16 f2bf(float f){
  union { float f; unsigned int i; } v; v.f = f;
  return (u16)((v.i + 0x7FFFu + ((v.i >> 16) & 1u)) >> 16);
}

// ---------------- LayerNorm + x->bf16 (one row per block) ----------------
__global__ void ln_prep(const float* __restrict__ x, const float* __restrict__ g,
                        const float* __restrict__ bta, u16* __restrict__ h,
                        u16* __restrict__ xb, float* __restrict__ loss){
  if (blockIdx.x == 0 && threadIdx.x == 0) loss[0] = 0.f;
  int row = blockIdx.x, tid = threadIdx.x;
  const float4* xr = (const float4*)(x + (size_t)row * 1024);
  float4 v = xr[tid];
  float s  = v.x + v.y + v.z + v.w;
  float s2 = v.x*v.x + v.y*v.y + v.z*v.z + v.w*v.w;
  #pragma unroll
  for (int o = 32; o > 0; o >>= 1){ s += __shfl_down(s, o); s2 += __shfl_down(s2, o); }
  __shared__ float red[8];
  if ((tid & 63) == 0){ red[tid >> 6] = s; red[4 + (tid >> 6)] = s2; }
  __syncthreads();
  float ts = red[0]+red[1]+red[2]+red[3];
  float t2 = red[4]+red[5]+red[6]+red[7];
  float mu   = ts * (1.0f/1024.0f);
  float var  = t2 * (1.0f/1024.0f) - mu*mu;
  float rstd = rsqrtf(var + 1e-5f);
  float4 gg = ((const float4*)g)[tid];
  float4 bb = ((const float4*)bta)[tid];
  ushort4 hv, xv;
  hv.x = f2bf((v.x-mu)*rstd*gg.x + bb.x);
  hv.y = f2bf((v.y-mu)*rstd*gg.y + bb.y);
  hv.z = f2bf((v.z-mu)*rstd*gg.z + bb.z);
  hv.w = f2bf((v.w-mu)*rstd*gg.w + bb.w);
  xv.x = f2bf(v.x); xv.y = f2bf(v.y); xv.z = f2bf(v.z); xv.w = f2bf(v.w);
  ((ushort4*)h )[(size_t)row*256 + tid] = hv;
  ((ushort4*)xb)[(size_t)row*256 + tid] = xv;
}

// ---------------- fp32 -> bf16 weight conversion (5 matrices) ----------------
__global__ void conv5(const float* __restrict__ a, const float* __restrict__ b,
                      const float* __restrict__ c, const float* __restrict__ d,
                      const float* __restrict__ e,
                      u16* oa, u16* ob, u16* oc, u16* od, u16* oe){
  int sel = blockIdx.y;
  const float* s = sel==0?a : sel==1?b : sel==2?c : sel==3?d : e;
  u16* o = sel==0?oa : sel==1?ob : sel==2?oc : sel==3?od : oe;
  int i = blockIdx.x*256 + threadIdx.x;
  float4 v = ((const float4*)s)[i];
  ushort4 r; r.x=f2bf(v.x); r.y=f2bf(v.y); r.z=f2bf(v.z); r.w=f2bf(v.w);
  ((ushort4*)o)[i] = r;
}

// --------- WeffT[d][e] = W0[e][d] + sum_r A[e][r]*B[r][d], bf16 out ---------
__global__ void weff_k(const float* __restrict__ W0, const float* __restrict__ Ai,
                       const float* __restrict__ Bi, u16* __restrict__ Wet){
  __shared__ float tile[32][33];
  int d0 = blockIdx.x*32, e0 = blockIdx.y*32;
  int tid = threadIdx.x;
  int lr = tid >> 5, lc = tid & 31;
  #pragma unroll
  for (int s = 0; s < 4; ++s){
    int e = e0 + s*8 + lr, d = d0 + lc;
    float v = W0[(size_t)e*1024 + d];
    #pragma unroll
    for (int r = 0; r < 8; ++r) v += Ai[e*8 + r] * Bi[(size_t)r*1024 + d];
    tile[s*8 + lr][lc] = v;
  }
  __syncthreads();
  #pragma unroll
  for (int s = 0; s < 4; ++s){
    int d = d0 + s*8 + lr, e = e0 + lc;
    Wet[(size_t)d*1024 + e] = f2bf(tile[lc][s*8 + lr]);
  }
}

// ----- prep tables: pos_scale, lr clamp; zero look-back flags + ticket ------
__global__ void psk2(const float* __restrict__ llr, float* __restrict__ psg,
                     float* __restrict__ lrc, unsigned* __restrict__ flags,
                     unsigned* __restrict__ ticket){
  int t = blockIdx.x*256 + threadIdx.x;   // 0..4095
  psg[t] = 1.0f/(1.0f + 0.1f*logf((float)(t+1)));
  if (t < 1024){ lrc[t] = fminf(expf(llr[t]), 1.0f); flags[t] = 0u; }
  if (t == 0) *ticket = 0u;
}

// ---------------- MFMA GEMM: C[m,n] = sum_k A[m,k]*Bm[n,k]  (K=1024) --------
// 128x128 tile, BK=64, 256 thr = 4 waves (2x2), each wave 4x4 of 16x16x32.
// LDS XOR-swizzled: chunk slot c' of row r holds k-chunk c'^(r&7).
// EPI: 0 = bf16 direct store; 1 = fp32 *ls_g + residual via LDS round-trip.
template<int EPI>
__device__ __forceinline__ void gemm_body(const u16* __restrict__ A, const u16* __restrict__ Bm,
    u16* __restrict__ Cb, float* __restrict__ Cf, const float* __restrict__ lsg,
    const float* __restrict__ xres, int mblk, int nblk){
  __shared__ u16 smem[16384];
  u16* As = smem;
  u16* Bs = smem + 8192;
  const int tid  = threadIdx.x;
  const int lane = tid & 63;
  const int w    = tid >> 6;
  const int m0 = mblk * 128, n0 = nblk * 128;
  const int lrow = lane >> 3;
  const int gcol8 = (((lane & 7) ^ (lrow & 7)) * 8);
  const int wm = w & 1, wn = w >> 1;
  const int l15 = lane & 15, quad = lane >> 4;
  const int sw  = (l15 & 7);

  f32x4 acc[4][4] = {};

  #pragma unroll 1
  for (int kk = 0; kk < 1024; kk += 64){
    #pragma unroll
    for (int it = 0; it < 4; ++it){
      int r0 = w*8 + it*32;
      const u16* ga = A  + (size_t)(m0 + r0 + lrow)*1024 + kk + gcol8;
      __builtin_amdgcn_global_load_lds((const __attribute__((address_space(1))) unsigned int*)ga,
          (__attribute__((address_space(3))) unsigned int*)(As + r0*64), 16, 0, 0);
      const u16* gb = Bm + (size_t)(n0 + r0 + lrow)*1024 + kk + gcol8;
      __builtin_amdgcn_global_load_lds((const __attribute__((address_space(1))) unsigned int*)gb,
          (__attribute__((address_space(3))) unsigned int*)(Bs + r0*64), 16, 0, 0);
    }
    __syncthreads();
    #pragma unroll
    for (int kh = 0; kh < 2; ++kh){
      int kbi = kh*4 + quad;
      int koff = ((kbi ^ sw) * 8);
      short8 af[4], bfv[4];
      #pragma unroll
      for (int i = 0; i < 4; ++i) af[i]  = *(const short8*)(As + (wm*64 + i*16 + l15)*64 + koff);
      #pragma unroll
      for (int j = 0; j < 4; ++j) bfv[j] = *(const short8*)(Bs + (wn*64 + j*16 + l15)*64 + koff);
      #pragma unroll
      for (int i = 0; i < 4; ++i)
        #pragma unroll
        for (int j = 0; j < 4; ++j)
          acc[i][j] = __builtin_amdgcn_mfma_f32_16x16x32_bf16(af[i], bfv[j], acc[i][j], 0, 0, 0);
    }
    __syncthreads();
  }

  const int rbase = quad * 4;
  if (EPI == 0){
    #pragma unroll
    for (int i = 0; i < 4; ++i){
      int row = m0 + wm*64 + i*16 + rbase;
      #pragma unroll
      for (int j = 0; j < 4; ++j){
        int col = n0 + wn*64 + j*16 + l15;
        #pragma unroll
        for (int r = 0; r < 4; ++r)
          Cb[(size_t)(row + r)*1024 + col] = f2bf(acc[i][j][r]);
      }
    }
  } else {
    // LDS round-trip: 4 chunks of 32 rows; coalesced float4 epilogue
    float* cf = (float*)smem;
    const int lr = tid >> 3, seg = tid & 7;
    float4 lsv[4];
    #pragma unroll
    for (int k = 0; k < 4; ++k) lsv[k] = *(const float4*)(lsg + n0 + seg*16 + k*4);
    #pragma unroll
    for (int i = 0; i < 4; ++i){
      __syncthreads();
      #pragma unroll
      for (int j = 0; j < 4; ++j)
        #pragma unroll
        for (int r = 0; r < 4; ++r)
          cf[(wm*16 + rbase + r)*132 + wn*64 + j*16 + l15] = acc[i][j][r];
      __syncthreads();
      int grow = m0 + i*16 + (lr & 15) + (lr >> 4)*64;
      size_t gbase = (size_t)grow*1024 + n0 + seg*16;
      #pragma unroll
      for (int k = 0; k < 4; ++k){
        float4 o = *(const float4*)(cf + lr*132 + seg*16 + k*4);
        float4 xr = *(const float4*)(xres + gbase + k*4);
        float4 res;
        res.x = o.x*lsv[k].x + xr.x; res.y = o.y*lsv[k].y + xr.y;
        res.z = o.z*lsv[k].z + xr.z; res.w = o.w*lsv[k].w + xr.w;
        *(float4*)(Cf + gbase + k*4) = res;
      }
    }
  }
}

// fused Q/K/V/Gate GEMM: grid (128, 32); blockIdx.y>>3 selects output
__global__ void gemm_qkvg(const u16* __restrict__ h, const u16* __restrict__ xb,
                          const u16* __restrict__ Wqb, const u16* __restrict__ Wkb,
                          const u16* __restrict__ Wvb, const u16* __restrict__ Wgb,
                          u16* __restrict__ Qb, u16* __restrict__ Kb,
                          u16* __restrict__ Vb, u16* __restrict__ Gb){
  int sel = blockIdx.y >> 3;
  const u16* A  = (sel == 3) ? xb : h;
  const u16* Bm = sel==0?Wqb : sel==1?Wkb : sel==2?Wvb : Wgb;
  u16* Out      = sel==0?Qb  : sel==1?Kb  : sel==2?Vb  : Gb;
  gemm_body<0>(A, Bm, Out, nullptr, nullptr, nullptr, blockIdx.x, blockIdx.y & 7);
}

__global__ void gemm_final(const u16* __restrict__ A, const u16* __restrict__ Bm,
                           float* __restrict__ C, const float* __restrict__ lsg,
                           const float* __restrict__ xres){
  gemm_body<1>(A, Bm, nullptr, C, lsg, xres, blockIdx.x, blockIdx.y);
}

// ======= y0 GEMM + fused TTT scan via decoupled look-back (ticketed) ========
// grid 1024 blocks; ticket t: ch = t>>5 (time chunk), b = (t&31)>>3, nblk = t&7
// chain = b*8+nblk (32 chains x 32 links). Writes out_pre in place of Q.
__global__ void gemm_y0_scan(const u16* __restrict__ Kb, const u16* __restrict__ Wet,
                             const u16* __restrict__ Vb, const u16* Qb,
                             const u16* __restrict__ Gb,
                             const float* __restrict__ lrc, const float* __restrict__ psg,
                             u16* OutPre, float* __restrict__ Incl,
                             unsigned* __restrict__ flags, unsigned* __restrict__ ticket,
                             float* __restrict__ loss){
  __shared__ u16 smem[17424];                 // 34,848 B -> 4 blocks/CU
  u16* As = smem;
  u16* Bs = smem + 8192;
  __shared__ unsigned tk_s;
  const int tid  = threadIdx.x;
  const int lane = tid & 63;
  const int w    = tid >> 6;
  if (tid == 0) tk_s = atomicAdd(ticket, 1u);
  __syncthreads();
  const unsigned tk = tk_s;
  const int ch = tk >> 5, sub = tk & 31;
  const int chain = sub;                       // b*8 + nblk
  const int b = sub >> 3, nblk = sub & 7;
  const int mblk = b*32 + ch;
  const int m0 = mblk * 128, n0 = nblk * 128;
  const int lrow = lane >> 3;
  const int gcol8 = (((lane & 7) ^ (lrow & 7)) * 8);
  const int wm = w & 1, wn = w >> 1;
  const int l15 = lane & 15, quad = lane >> 4;
  const int sw  = (l15 & 7);

  f32x4 acc[4][4] = {};

  #pragma unroll 1
  for (int kk = 0; kk < 1024; kk += 64){
    #pragma unroll
    for (int it = 0; it < 4; ++it){
      int r0 = w*8 + it*32;
      const u16* ga = Kb  + (size_t)(m0 + r0 + lrow)*1024 + kk + gcol8;
      __builtin_amdgcn_global_load_lds((const __attribute__((address_space(1))) unsigned int*)ga,
          (__attribute__((address_space(3))) unsigned int*)(As + r0*64), 16, 0, 0);
      const u16* gb = Wet + (size_t)(n0 + r0 + lrow)*1024 + kk + gcol8;
      __builtin_amdgcn_global_load_lds((const __attribute__((address_space(1))) unsigned int*)gb,
          (__attribute__((address_space(3))) unsigned int*)(Bs + r0*64), 16, 0, 0);
    }
    __syncthreads();
    #pragma unroll
    for (int kh = 0; kh < 2; ++kh){
      int kbi = kh*4 + quad;
      int koff = ((kbi ^ sw) * 8);
      short8 af[4], bfv[4];
      #pragma unroll
      for (int i = 0; i < 4; ++i) af[i]  = *(const short8*)(As + (wm*64 + i*16 + l15)*64 + koff);
      #pragma unroll
      for (int j = 0; j < 4; ++j) bfv[j] = *(const short8*)(Bs + (wn*64 + j*16 + l15)*64 + koff);
      #pragma unroll
      for (int i = 0; i < 4; ++i)
        #pragma unroll
        for (int j = 0; j < 4; ++j)
          acc[i][j] = __builtin_amdgcn_mfma_f32_16x16x32_bf16(af[i], bfv[j], acc[i][j], 0, 0, 0);
    }
    __syncthreads();
  }

  const int rbase = quad * 4;
  u16*  gvt  = smem;                           // [row][132] bf16 gv tile
  float* aggf = (float*)(smem + 16896);        // 256 col-aggs + 4 loss slots

  // e = y0 - V (fp32), gv = K*e; column aggregates + loss; gv -> LDS
  float csum[4] = {0.f, 0.f, 0.f, 0.f};
  float ls = 0.f;
  #pragma unroll
  for (int i = 0; i < 4; ++i){
    int rowl = wm*64 + i*16 + rbase;
    #pragma unroll
    for (int j = 0; j < 4; ++j){
      int coll = wn*64 + j*16 + l15;
      #pragma unroll
      for (int r = 0; r < 4; ++r){
        size_t idx = (size_t)(m0 + rowl + r)*1024 + n0 + coll;
        float y  = acc[i][j][r];
        float kv = bf2f(Kb[idx]);
        float vv = bf2f(Vb[idx]);
        float e  = y - vv;
        float gv = kv * e;
        ls += e*e;
        csum[j] += gv;
        gvt[(rowl + r)*132 + coll] = f2bf(gv);
      }
    }
  }
  #pragma unroll
  for (int j = 0; j < 4; ++j){
    csum[j] += __shfl_xor(csum[j], 16);
    csum[j] += __shfl_xor(csum[j], 32);
  }
  if (quad == 0){
    #pragma unroll
    for (int j = 0; j < 4; ++j) aggf[wm*128 + wn*64 + j*16 + l15] = csum[j];
  }
  #pragma unroll
  for (int o = 32; o > 0; o >>= 1) ls += __shfl_down(ls, o);
  if (lane == 0) aggf[256 + w] = ls;
  __syncthreads();

  // decoupled look-back: publish inclusive prefix for this chunk
  float P = 0.f;
  if (tid < 128){
    float aggc = aggf[tid] + aggf[128 + tid];
    if (ch > 0){
      const unsigned fi = chain*32 + ch - 1;
      while (__hip_atomic_load(&flags[fi], __ATOMIC_ACQUIRE, __HIP_MEMORY_SCOPE_AGENT) == 0u)
        __builtin_amdgcn_s_sleep(8);
      P = __hip_atomic_load(&Incl[(size_t)fi*128 + tid], __ATOMIC_RELAXED, __HIP_MEMORY_SCOPE_AGENT);
    }
    __hip_atomic_store(&Incl[((size_t)chain*32 + ch)*128 + tid], P + aggc,
                       __ATOMIC_RELAXED, __HIP_MEMORY_SCOPE_AGENT);
  }
  __syncthreads();   // drain vmcnt: Incl stores done before flag
  if (tid == 0)
    __hip_atomic_store(&flags[chain*32 + ch], 1u, __ATOMIC_RELEASE, __HIP_MEMORY_SCOPE_AGENT);

  // in-tile exclusive column scan (run overwrites gv in LDS)
  if (tid < 128){
    float run = P;
    u16* colp = gvt + tid;
    #pragma unroll 4
    for (int t = 0; t < 128; ++t){
      float g = bf2f(colp[t*132]);
      colp[t*132] = f2bf(run);
      run += g;
    }
  }
  __syncthreads();

  // out_pre = (y0 - Q*lr*run*ps) * sigmoid(G), in place of Q
  #pragma unroll
  for (int i = 0; i < 4; ++i){
    int rowl = wm*64 + i*16 + rbase;
    #pragma unroll
    for (int j = 0; j < 4; ++j){
      int coll = wn*64 + j*16 + l15;
      float lrcv = lrc[n0 + coll];
      #pragma unroll
      for (int r = 0; r < 4; ++r){
        size_t idx = (size_t)(m0 + rowl + r)*1024 + n0 + coll;
        float run = bf2f(gvt[(rowl + r)*132 + coll]);
        float ps  = psg[ch*128 + rowl + r];
        float q   = bf2f(Qb[idx]);
        float gl  = bf2f(Gb[idx]);
        float gate = 1.0f/(1.0f + expf(-gl));
        float o = (acc[i][j][r] - q*lrcv*run*ps) * gate;
        OutPre[idx] = f2bf(o);
      }
    }
  }
  if (tid == 0) atomicAdd(loss, aggf[256]+aggf[257]+aggf[258]+aggf[259]);
}

__global__ void finloss(const float* __restrict__ loss, float* __restrict__ o){
  o[0] = loss[0] * (1.0f/16777216.0f);
}

extern "C" void kernel_launch(void* const* d_in, const int* in_sizes, int n_in,
                              void* d_out, int out_size, void* d_ws, size_t ws_size,
                              hipStream_t stream){
  const float* x   = (const float*)d_in[0];
  const float* W0  = (const float*)d_in[1];
  const float* Ai  = (const float*)d_in[2];
  const float* Bi  = (const float*)d_in[3];
  const float* llr = (const float*)d_in[4];
  const float* Wq  = (const float*)d_in[5];
  const float* Wk  = (const float*)d_in[6];
  const float* Wv  = (const float*)d_in[7];
  const float* Wo  = (const float*)d_in[8];
  const float* Wg  = (const float*)d_in[9];
  const float* lng = (const float*)d_in[10];
  const float* lnb = (const float*)d_in[11];
  const float* lsg = (const float*)d_in[12];
  float* out = (float*)d_out;

  const size_t TOK = 16384, CC = 1024;
  char* p = (char*)d_ws;
  float* loss = (float*)p; p += 256;
  u16* h   = (u16*)p; p += TOK*CC*2;
  u16* xb  = (u16*)p; p += TOK*CC*2;
  u16* Qb  = (u16*)p; p += TOK*CC*2;   // becomes out_pre in gemm_y0_scan
  u16* Kb  = (u16*)p; p += TOK*CC*2;
  u16* Vb  = (u16*)p; p += TOK*CC*2;
  u16* Gb  = (u16*)p; p += TOK*CC*2;
  u16* Wqb = (u16*)p; p += CC*CC*2;
  u16* Wkb = (u16*)p; p += CC*CC*2;
  u16* Wvb = (u16*)p; p += CC*CC*2;
  u16* Wgb = (u16*)p; p += CC*CC*2;
  u16* Wob = (u16*)p; p += CC*CC*2;
  u16* Wet = (u16*)p; p += CC*CC*2;
  float*    psg    = (float*)p;    p += 4096*4;
  float*    lrc    = (float*)p;    p += 1024*4;
  float*    Incl   = (float*)p;    p += (size_t)1024*128*4;
  unsigned* flags  = (unsigned*)p; p += 1024*4;
  unsigned* ticket = (unsigned*)p; p += 256;

  ln_prep<<<16384, 256, 0, stream>>>(x, lng, lnb, h, xb, loss);
  conv5<<<dim3(1024, 5), 256, 0, stream>>>(Wq, Wk, Wv, Wg, Wo, Wqb, Wkb, Wvb, Wgb, Wob);
  weff_k<<<dim3(32, 32), 256, 0, stream>>>(W0, Ai, Bi, Wet);
  psk2<<<16, 256, 0, stream>>>(llr, psg, lrc, flags, ticket);
  gemm_qkvg<<<dim3(128, 32), 256, 0, stream>>>(h, xb, Wqb, Wkb, Wvb, Wgb, Qb, Kb, Vb, Gb);
  gemm_y0_scan<<<1024, 256, 0, stream>>>(Kb, Wet, Vb, Qb, Gb, lrc, psg, Qb,
                                         Incl, flags, ticket, loss);
  gemm_final<<<dim3(128, 8), 256, 0, stream>>>(Qb, Wob, out, lsg, x);
  finloss<<<1, 1, 0, stream>>>(loss, out + 16777216);
}

// Round 5
// 517.938 us; speedup vs baseline: 2.4017x; 2.4017x over previous
//
#include <hip/hip_runtime.h>
#include <stdint.h>
#include <math.h>

typedef unsigned short u16;
typedef __attribute__((ext_vector_type(8))) short short8;
typedef __attribute__((ext_vector_type(4))) float f32x4;

__device__ __forceinline__ float bf2f(u16 u){
  union { unsigned int i; float f; } v; v.i = ((unsigned int)u) << 16; return v.f;
}
__device__ __forceinline__ u16 f2bf(float f){
  union { float f; unsigned int i; } v; v.f = f;
  return (u16)((v.i + 0x7FFFu + ((v.i >> 16) & 1u)) >> 16);
}

// ---------------- LayerNorm + x->bf16 (one row per block) ----------------
__global__ void ln_prep(const float* __restrict__ x, const float* __restrict__ g,
                        const float* __restrict__ bta, u16* __restrict__ h,
                        u16* __restrict__ xb, float* __restrict__ loss){
  if (blockIdx.x == 0 && threadIdx.x == 0) loss[0] = 0.f;
  int row = blockIdx.x, tid = threadIdx.x;
  const float4* xr = (const float4*)(x + (size_t)row * 1024);
  float4 v = xr[tid];
  float s  = v.x + v.y + v.z + v.w;
  float s2 = v.x*v.x + v.y*v.y + v.z*v.z + v.w*v.w;
  #pragma unroll
  for (int o = 32; o > 0; o >>= 1){ s += __shfl_down(s, o); s2 += __shfl_down(s2, o); }
  __shared__ float red[8];
  if ((tid & 63) == 0){ red[tid >> 6] = s; red[4 + (tid >> 6)] = s2; }
  __syncthreads();
  float ts = red[0]+red[1]+red[2]+red[3];
  float t2 = red[4]+red[5]+red[6]+red[7];
  float mu   = ts * (1.0f/1024.0f);
  float var  = t2 * (1.0f/1024.0f) - mu*mu;
  float rstd = rsqrtf(var + 1e-5f);
  float4 gg = ((const float4*)g)[tid];
  float4 bb = ((const float4*)bta)[tid];
  ushort4 hv, xv;
  hv.x = f2bf((v.x-mu)*rstd*gg.x + bb.x);
  hv.y = f2bf((v.y-mu)*rstd*gg.y + bb.y);
  hv.z = f2bf((v.z-mu)*rstd*gg.z + bb.z);
  hv.w = f2bf((v.w-mu)*rstd*gg.w + bb.w);
  xv.x = f2bf(v.x); xv.y = f2bf(v.y); xv.z = f2bf(v.z); xv.w = f2bf(v.w);
  ((ushort4*)h )[(size_t)row*256 + tid] = hv;
  ((ushort4*)xb)[(size_t)row*256 + tid] = xv;
}

// ------- fused prep: conv5 (bx<5120) | weff (bx<6144) | tables (rest) -------
__global__ void prep_misc(const float* __restrict__ Wq, const float* __restrict__ Wk,
                          const float* __restrict__ Wv, const float* __restrict__ Wg,
                          const float* __restrict__ Wo, const float* __restrict__ W0,
                          const float* __restrict__ Ai, const float* __restrict__ Bi,
                          const float* __restrict__ llr,
                          u16* __restrict__ Wqb, u16* __restrict__ Wkb,
                          u16* __restrict__ Wvb, u16* __restrict__ Wgb,
                          u16* __restrict__ Wob, u16* __restrict__ Wet,
                          float* __restrict__ psg, float* __restrict__ lrc){
  int bx = blockIdx.x, tid = threadIdx.x;
  if (bx < 5120){
    int sel = bx >> 10;
    const float* s = sel==0?Wq : sel==1?Wk : sel==2?Wv : sel==3?Wg : Wo;
    u16* o = sel==0?Wqb : sel==1?Wkb : sel==2?Wvb : sel==3?Wgb : Wob;
    int i = (bx & 1023)*256 + tid;
    float4 v = ((const float4*)s)[i];
    ushort4 r; r.x=f2bf(v.x); r.y=f2bf(v.y); r.z=f2bf(v.z); r.w=f2bf(v.w);
    ((ushort4*)o)[i] = r;
  } else if (bx < 6144){
    __shared__ float tile[32][33];
    int wb = bx - 5120;
    int d0 = (wb & 31)*32, e0 = (wb >> 5)*32;
    int lr = tid >> 5, lc = tid & 31;
    #pragma unroll
    for (int s = 0; s < 4; ++s){
      int e = e0 + s*8 + lr, d = d0 + lc;
      float v = W0[(size_t)e*1024 + d];
      #pragma unroll
      for (int r = 0; r < 8; ++r) v += Ai[e*8 + r] * Bi[(size_t)r*1024 + d];
      tile[s*8 + lr][lc] = v;
    }
    __syncthreads();
    #pragma unroll
    for (int s = 0; s < 4; ++s){
      int d = d0 + s*8 + lr, e = e0 + lc;
      Wet[(size_t)d*1024 + e] = f2bf(tile[lc][s*8 + lr]);
    }
  } else {
    int t = (bx - 6144)*256 + tid;   // 0..4095
    psg[t] = 1.0f/(1.0f + 0.1f*logf((float)(t+1)));
    if (t < 1024) lrc[t] = fminf(expf(llr[t]), 1.0f);
  }
}

// ---------------- MFMA GEMM: C[m,n] = sum_k A[m,k]*Bm[n,k]  (K=1024) --------
// 128x128 tile, BK=64, 256 thr = 4 waves (2x2), each wave 4x4 of 16x16x32.
// LDS XOR-swizzled: chunk slot c' of row r holds k-chunk c'^(r&7) -> 0 conflicts.
// EPI: 0 = bf16 direct store; 1 = fp32 *ls_g + residual via LDS round-trip.
template<int EPI>
__device__ __forceinline__ void gemm_body(const u16* __restrict__ A, const u16* __restrict__ Bm,
    u16* __restrict__ Cb, float* __restrict__ Cf, const float* __restrict__ lsg,
    const float* __restrict__ xres, int mblk, int nblk){
  __shared__ u16 smem[16384];
  u16* As = smem;
  u16* Bs = smem + 8192;
  const int tid  = threadIdx.x;
  const int lane = tid & 63;
  const int w    = tid >> 6;
  const int m0 = mblk * 128, n0 = nblk * 128;
  const int lrow = lane >> 3;
  const int gcol8 = (((lane & 7) ^ (lrow & 7)) * 8);
  const int wm = w & 1, wn = w >> 1;
  const int l15 = lane & 15, quad = lane >> 4;
  const int sw  = (l15 & 7);

  f32x4 acc[4][4] = {};

  #pragma unroll 1
  for (int kk = 0; kk < 1024; kk += 64){
    #pragma unroll
    for (int it = 0; it < 4; ++it){
      int r0 = w*8 + it*32;
      const u16* ga = A  + (size_t)(m0 + r0 + lrow)*1024 + kk + gcol8;
      __builtin_amdgcn_global_load_lds((const __attribute__((address_space(1))) unsigned int*)ga,
          (__attribute__((address_space(3))) unsigned int*)(As + r0*64), 16, 0, 0);
      const u16* gb = Bm + (size_t)(n0 + r0 + lrow)*1024 + kk + gcol8;
      __builtin_amdgcn_global_load_lds((const __attribute__((address_space(1))) unsigned int*)gb,
          (__attribute__((address_space(3))) unsigned int*)(Bs + r0*64), 16, 0, 0);
    }
    __syncthreads();
    #pragma unroll
    for (int kh = 0; kh < 2; ++kh){
      int kbi = kh*4 + quad;
      int koff = ((kbi ^ sw) * 8);
      short8 af[4], bfv[4];
      #pragma unroll
      for (int i = 0; i < 4; ++i) af[i]  = *(const short8*)(As + (wm*64 + i*16 + l15)*64 + koff);
      #pragma unroll
      for (int j = 0; j < 4; ++j) bfv[j] = *(const short8*)(Bs + (wn*64 + j*16 + l15)*64 + koff);
      #pragma unroll
      for (int i = 0; i < 4; ++i)
        #pragma unroll
        for (int j = 0; j < 4; ++j)
          acc[i][j] = __builtin_amdgcn_mfma_f32_16x16x32_bf16(af[i], bfv[j], acc[i][j], 0, 0, 0);
    }
    __syncthreads();
  }

  const int rbase = quad * 4;
  if (EPI == 0){
    #pragma unroll
    for (int i = 0; i < 4; ++i){
      int row = m0 + wm*64 + i*16 + rbase;
      #pragma unroll
      for (int j = 0; j < 4; ++j){
        int col = n0 + wn*64 + j*16 + l15;
        #pragma unroll
        for (int r = 0; r < 4; ++r)
          Cb[(size_t)(row + r)*1024 + col] = f2bf(acc[i][j][r]);
      }
    }
  } else {
    // LDS round-trip: 4 chunks of 32 rows; coalesced float4 epilogue
    float* cf = (float*)smem;
    const int lr = tid >> 3, seg = tid & 7;
    float4 lsv[4];
    #pragma unroll
    for (int k = 0; k < 4; ++k) lsv[k] = *(const float4*)(lsg + n0 + seg*16 + k*4);
    #pragma unroll
    for (int i = 0; i < 4; ++i){
      __syncthreads();
      #pragma unroll
      for (int j = 0; j < 4; ++j)
        #pragma unroll
        for (int r = 0; r < 4; ++r)
          cf[(wm*16 + rbase + r)*132 + wn*64 + j*16 + l15] = acc[i][j][r];
      __syncthreads();
      int grow = m0 + i*16 + (lr & 15) + (lr >> 4)*64;
      size_t gbase = (size_t)grow*1024 + n0 + seg*16;
      #pragma unroll
      for (int k = 0; k < 4; ++k){
        float4 o = *(const float4*)(cf + lr*132 + seg*16 + k*4);
        float4 xr = *(const float4*)(xres + gbase + k*4);
        float4 res;
        res.x = o.x*lsv[k].x + xr.x; res.y = o.y*lsv[k].y + xr.y;
        res.z = o.z*lsv[k].z + xr.z; res.w = o.w*lsv[k].w + xr.w;
        *(float4*)(Cf + gbase + k*4) = res;
      }
    }
  }
}

// fused Q/K/V/Gate GEMM: grid (128, 32); blockIdx.y>>3 selects output
__global__ void gemm_qkvg(const u16* __restrict__ h, const u16* __restrict__ xb,
                          const u16* __restrict__ Wqb, const u16* __restrict__ Wkb,
                          const u16* __restrict__ Wvb, const u16* __restrict__ Wgb,
                          u16* __restrict__ Qb, u16* __restrict__ Kb,
                          u16* __restrict__ Vb, u16* __restrict__ Gb){
  int sel = blockIdx.y >> 3;
  const u16* A  = (sel == 3) ? xb : h;
  const u16* Bm = sel==0?Wqb : sel==1?Wkb : sel==2?Wvb : Wgb;
  u16* Out      = sel==0?Qb  : sel==1?Kb  : sel==2?Vb  : Gb;
  gemm_body<0>(A, Bm, Out, nullptr, nullptr, nullptr, blockIdx.x, blockIdx.y & 7);
}

__global__ void gemm_y0(const u16* __restrict__ Kb, const u16* __restrict__ Wet,
                        u16* __restrict__ Yb){
  gemm_body<0>(Kb, Wet, Yb, nullptr, nullptr, nullptr, blockIdx.x, blockIdx.y);
}

__global__ void gemm_final(const u16* __restrict__ A, const u16* __restrict__ Bm,
                           float* __restrict__ C, const float* __restrict__ lsg,
                           const float* __restrict__ xres){
  gemm_body<1>(A, Bm, nullptr, C, lsg, xres, blockIdx.x, blockIdx.y);
}

// ---- scan1: grad = K*(y0-V) -> Gr (bf16); per-chunk column sums; loss ------
// grid (4, 32, 4) = (cblock, chunk, batch); 128 thr, 2 channels/thread
__global__ void scan1(const u16* __restrict__ Kb, const u16* __restrict__ Vb,
                      const u16* __restrict__ Yb, u16* __restrict__ Gr,
                      float* __restrict__ part, float* __restrict__ loss){
  int tid = threadIdx.x;               // 0..127
  int c2  = blockIdx.x*128 + tid;      // ushort2 index
  int ch = blockIdx.y, b = blockIdx.z;
  size_t base = ((size_t)b*4096 + (size_t)ch*128)*512 + c2;
  const ushort2* K2 = (const ushort2*)Kb;
  const ushort2* V2 = (const ushort2*)Vb;
  const ushort2* Y2 = (const ushort2*)Yb;
  ushort2* G2 = (ushort2*)Gr;
  float g0 = 0.f, g1 = 0.f, ls = 0.f;
  #pragma unroll 8
  for (int t = 0; t < 128; ++t){
    size_t idx = base + (size_t)t*512;
    ushort2 kv = K2[idx], vv = V2[idx], yv = Y2[idx];
    float e0 = bf2f(yv.x) - bf2f(vv.x);
    float e1 = bf2f(yv.y) - bf2f(vv.y);
    float gv0 = bf2f(kv.x)*e0, gv1 = bf2f(kv.y)*e1;
    ushort2 gw; gw.x = f2bf(gv0); gw.y = f2bf(gv1);
    G2[idx] = gw;
    g0 += gv0; g1 += gv1; ls += e0*e0 + e1*e1;
  }
  float2 pw; pw.x = g0; pw.y = g1;
  *(float2*)(part + ((size_t)(b*32 + ch))*1024 + c2*2) = pw;
  #pragma unroll
  for (int o = 32; o > 0; o >>= 1) ls += __shfl_down(ls, o);
  __shared__ float red[2];
  if ((tid & 63) == 0) red[tid >> 6] = ls;
  __syncthreads();
  if (tid == 0) atomicAdd(loss, red[0] + red[1]);
}

// -- scan2: out_pre = (y0 - Q*lr*shift*ps)*sigmoid(G), in place of Q ---------
// grid (4, 32, 4); 128 thr, 2 channels/thread
__global__ void scan2(const u16* __restrict__ Gr, const u16* __restrict__ Yb,
                      const u16* __restrict__ Qb, const u16* __restrict__ Gb,
                      const float* __restrict__ part, const float* __restrict__ lrc,
                      const float* __restrict__ psg, u16* __restrict__ OutPre){
  int tid = threadIdx.x;               // 0..127
  int c2  = blockIdx.x*128 + tid;
  int ch = blockIdx.y, b = blockIdx.z;
  __shared__ float ps_s[128];
  ps_s[tid] = psg[ch*128 + tid];
  int c = c2*2;
  float run0 = 0.f, run1 = 0.f;
  for (int j = 0; j < ch; ++j){
    float2 pp = *(const float2*)(part + ((size_t)(b*32 + j))*1024 + c);
    run0 += pp.x; run1 += pp.y;
  }
  float2 lr2 = *(const float2*)(lrc + c);
  __syncthreads();
  size_t base = ((size_t)b*4096 + (size_t)ch*128)*512 + c2;
  const ushort2* Gr2 = (const ushort2*)Gr;
  const ushort2* Yb2 = (const ushort2*)Yb;
  const ushort2* Qb2 = (const ushort2*)Qb;
  const ushort2* Gb2 = (const ushort2*)Gb;
  ushort2* Ot2 = (ushort2*)OutPre;
  #pragma unroll 8
  for (int t = 0; t < 128; ++t){
    size_t idx = base + (size_t)t*512;
    ushort2 gr = Gr2[idx], yv = Yb2[idx], qv = Qb2[idx], gl = Gb2[idx];
    float ps = ps_s[t];
    float g0 = 1.0f/(1.0f + expf(-bf2f(gl.x)));
    float g1 = 1.0f/(1.0f + expf(-bf2f(gl.y)));
    float o0 = (bf2f(yv.x) - bf2f(qv.x)*lr2.x*run0*ps) * g0;
    float o1 = (bf2f(yv.y) - bf2f(qv.y)*lr2.y*run1*ps) * g1;
    ushort2 ov; ov.x = f2bf(o0); ov.y = f2bf(o1);
    Ot2[idx] = ov;                    // same buffer as Qb: read-before-write
    run0 += bf2f(gr.x); run1 += bf2f(gr.y);
  }
}

__global__ void finloss(const float* __restrict__ loss, float* __restrict__ o){
  o[0] = loss[0] * (1.0f/16777216.0f);
}

extern "C" void kernel_launch(void* const* d_in, const int* in_sizes, int n_in,
                              void* d_out, int out_size, void* d_ws, size_t ws_size,
                              hipStream_t stream){
  const float* x   = (const float*)d_in[0];
  const float* W0  = (const float*)d_in[1];
  const float* Ai  = (const float*)d_in[2];
  const float* Bi  = (const float*)d_in[3];
  const float* llr = (const float*)d_in[4];
  const float* Wq  = (const float*)d_in[5];
  const float* Wk  = (const float*)d_in[6];
  const float* Wv  = (const float*)d_in[7];
  const float* Wo  = (const float*)d_in[8];
  const float* Wg  = (const float*)d_in[9];
  const float* lng = (const float*)d_in[10];
  const float* lnb = (const float*)d_in[11];
  const float* lsg = (const float*)d_in[12];
  float* out = (float*)d_out;

  const size_t TOK = 16384, CC = 1024;
  char* p = (char*)d_ws;
  float* loss = (float*)p; p += 256;
  u16* h   = (u16*)p; p += TOK*CC*2;   // LN out; reused as y0 after gemm_y0
  u16* xb  = (u16*)p; p += TOK*CC*2;   // x bf16; reused as Gr after qkvg
  u16* Qb  = (u16*)p; p += TOK*CC*2;   // becomes out_pre in scan2
  u16* Kb  = (u16*)p; p += TOK*CC*2;
  u16* Vb  = (u16*)p; p += TOK*CC*2;
  u16* Gb  = (u16*)p; p += TOK*CC*2;
  u16* Wqb = (u16*)p; p += CC*CC*2;
  u16* Wkb = (u16*)p; p += CC*CC*2;
  u16* Wvb = (u16*)p; p += CC*CC*2;
  u16* Wgb = (u16*)p; p += CC*CC*2;
  u16* Wob = (u16*)p; p += CC*CC*2;
  u16* Wet = (u16*)p; p += CC*CC*2;
  float* psg  = (float*)p; p += 4096*4;
  float* lrc  = (float*)p; p += 1024*4;
  float* part = (float*)p; p += (size_t)128*1024*4;

  ln_prep<<<16384, 256, 0, stream>>>(x, lng, lnb, h, xb, loss);
  prep_misc<<<6160, 256, 0, stream>>>(Wq, Wk, Wv, Wg, Wo, W0, Ai, Bi, llr,
                                      Wqb, Wkb, Wvb, Wgb, Wob, Wet, psg, lrc);
  gemm_qkvg<<<dim3(128, 32), 256, 0, stream>>>(h, xb, Wqb, Wkb, Wvb, Wgb, Qb, Kb, Vb, Gb);
  gemm_y0<<<dim3(128, 8), 256, 0, stream>>>(Kb, Wet, h);
  scan1<<<dim3(4, 32, 4), 128, 0, stream>>>(Kb, Vb, h, xb, part, loss);
  scan2<<<dim3(4, 32, 4), 128, 0, stream>>>(xb, h, Qb, Gb, part, lrc, psg, Qb);
  gemm_final<<<dim3(128, 8), 256, 0, stream>>>(Qb, Wob, out, lsg, x);
  finloss<<<1, 1, 0, stream>>>(loss, out + 16777216);
}

// Round 6
// 514.943 us; speedup vs baseline: 2.4157x; 1.0058x over previous
//
#include <hip/hip_runtime.h>
#include <stdint.h>
#include <math.h>

typedef unsigned short u16;
typedef __attribute__((ext_vector_type(8))) short short8;
typedef __attribute__((ext_vector_type(4))) float f32x4;

__device__ __forceinline__ float bf2f(u16 u){
  union { unsigned int i; float f; } v; v.i = ((unsigned int)u) << 16; return v.f;
}
__device__ __forceinline__ u16 f2bf(float f){
  union { float f; unsigned int i; } v; v.f = f;
  return (u16)((v.i + 0x7FFFu + ((v.i >> 16) & 1u)) >> 16);
}

// ---- fused prep: LN rows (bx<16384) | conv5 | weff | tables ----------------
__global__ void prep_all(const float* __restrict__ x, const float* __restrict__ lng,
                         const float* __restrict__ lnb,
                         const float* __restrict__ Wq, const float* __restrict__ Wk,
                         const float* __restrict__ Wv, const float* __restrict__ Wg,
                         const float* __restrict__ Wo, const float* __restrict__ W0,
                         const float* __restrict__ Ai, const float* __restrict__ Bi,
                         const float* __restrict__ llr,
                         u16* __restrict__ h, u16* __restrict__ xb,
                         u16* __restrict__ Wqb, u16* __restrict__ Wkb,
                         u16* __restrict__ Wvb, u16* __restrict__ Wgb,
                         u16* __restrict__ Wob, u16* __restrict__ Wet,
                         float* __restrict__ psg, float* __restrict__ lrc,
                         float* __restrict__ loss){
  int bx = blockIdx.x, tid = threadIdx.x;
  if (bx < 16384){
    if (bx == 0 && tid == 0) loss[0] = 0.f;
    int row = bx;
    float4 v = ((const float4*)(x + (size_t)row * 1024))[tid];
    float s  = v.x + v.y + v.z + v.w;
    float s2 = v.x*v.x + v.y*v.y + v.z*v.z + v.w*v.w;
    #pragma unroll
    for (int o = 32; o > 0; o >>= 1){ s += __shfl_down(s, o); s2 += __shfl_down(s2, o); }
    __shared__ float red[8];
    if ((tid & 63) == 0){ red[tid >> 6] = s; red[4 + (tid >> 6)] = s2; }
    __syncthreads();
    float ts = red[0]+red[1]+red[2]+red[3];
    float t2 = red[4]+red[5]+red[6]+red[7];
    float mu   = ts * (1.0f/1024.0f);
    float var  = t2 * (1.0f/1024.0f) - mu*mu;
    float rstd = rsqrtf(var + 1e-5f);
    float4 gg = ((const float4*)lng)[tid];
    float4 bb = ((const float4*)lnb)[tid];
    ushort4 hv, xv;
    hv.x = f2bf((v.x-mu)*rstd*gg.x + bb.x);
    hv.y = f2bf((v.y-mu)*rstd*gg.y + bb.y);
    hv.z = f2bf((v.z-mu)*rstd*gg.z + bb.z);
    hv.w = f2bf((v.w-mu)*rstd*gg.w + bb.w);
    xv.x = f2bf(v.x); xv.y = f2bf(v.y); xv.z = f2bf(v.z); xv.w = f2bf(v.w);
    ((ushort4*)h )[(size_t)row*256 + tid] = hv;
    ((ushort4*)xb)[(size_t)row*256 + tid] = xv;
  } else if (bx < 21504){              // 5120 conv blocks
    int cb = bx - 16384;
    int sel = cb >> 10;
    const float* s = sel==0?Wq : sel==1?Wk : sel==2?Wv : sel==3?Wg : Wo;
    u16* o = sel==0?Wqb : sel==1?Wkb : sel==2?Wvb : sel==3?Wgb : Wob;
    int i = (cb & 1023)*256 + tid;
    float4 v = ((const float4*)s)[i];
    ushort4 r; r.x=f2bf(v.x); r.y=f2bf(v.y); r.z=f2bf(v.z); r.w=f2bf(v.w);
    ((ushort4*)o)[i] = r;
  } else if (bx < 22528){              // 1024 weff blocks
    __shared__ float tile[32][33];
    int wb = bx - 21504;
    int d0 = (wb & 31)*32, e0 = (wb >> 5)*32;
    int lr = tid >> 5, lc = tid & 31;
    #pragma unroll
    for (int s = 0; s < 4; ++s){
      int e = e0 + s*8 + lr, d = d0 + lc;
      float v = W0[(size_t)e*1024 + d];
      #pragma unroll
      for (int r = 0; r < 8; ++r) v += Ai[e*8 + r] * Bi[(size_t)r*1024 + d];
      tile[s*8 + lr][lc] = v;
    }
    __syncthreads();
    #pragma unroll
    for (int s = 0; s < 4; ++s){
      int d = d0 + s*8 + lr, e = e0 + lc;
      Wet[(size_t)d*1024 + e] = f2bf(tile[lc][s*8 + lr]);
    }
  } else {                             // 16 table blocks
    int t = (bx - 22528)*256 + tid;    // 0..4095
    psg[t] = 1.0f/(1.0f + 0.1f*logf((float)(t+1)));
    if (t < 1024) lrc[t] = fminf(expf(llr[t]), 1.0f);
  }
}

// ---------------- MFMA GEMM: C[m,n] = sum_k A[m,k]*Bm[n,k]  (K=1024) --------
// 128x128 tile, BK=64, 256 thr = 4 waves (2x2), each wave 4x4 of 16x16x32.
// LDS XOR-swizzled: chunk slot c' of row r holds k-chunk c'^(r&7) -> 0 conflicts.
// EPI: 0 = bf16 direct store; 1 = fp32 *ls_g + residual via LDS round-trip.
template<int EPI>
__device__ __forceinline__ void gemm_body(const u16* __restrict__ A, const u16* __restrict__ Bm,
    u16* __restrict__ Cb, float* __restrict__ Cf, const float* __restrict__ lsg,
    const float* __restrict__ xres, int mblk, int nblk){
  __shared__ u16 smem[16384];
  u16* As = smem;
  u16* Bs = smem + 8192;
  const int tid  = threadIdx.x;
  const int lane = tid & 63;
  const int w    = tid >> 6;
  const int m0 = mblk * 128, n0 = nblk * 128;
  const int lrow = lane >> 3;
  const int gcol8 = (((lane & 7) ^ (lrow & 7)) * 8);
  const int wm = w & 1, wn = w >> 1;
  const int l15 = lane & 15, quad = lane >> 4;
  const int sw  = (l15 & 7);

  f32x4 acc[4][4] = {};

  #pragma unroll 1
  for (int kk = 0; kk < 1024; kk += 64){
    #pragma unroll
    for (int it = 0; it < 4; ++it){
      int r0 = w*8 + it*32;
      const u16* ga = A  + (size_t)(m0 + r0 + lrow)*1024 + kk + gcol8;
      __builtin_amdgcn_global_load_lds((const __attribute__((address_space(1))) unsigned int*)ga,
          (__attribute__((address_space(3))) unsigned int*)(As + r0*64), 16, 0, 0);
      const u16* gb = Bm + (size_t)(n0 + r0 + lrow)*1024 + kk + gcol8;
      __builtin_amdgcn_global_load_lds((const __attribute__((address_space(1))) unsigned int*)gb,
          (__attribute__((address_space(3))) unsigned int*)(Bs + r0*64), 16, 0, 0);
    }
    __syncthreads();
    #pragma unroll
    for (int kh = 0; kh < 2; ++kh){
      int kbi = kh*4 + quad;
      int koff = ((kbi ^ sw) * 8);
      short8 af[4], bfv[4];
      #pragma unroll
      for (int i = 0; i < 4; ++i) af[i]  = *(const short8*)(As + (wm*64 + i*16 + l15)*64 + koff);
      #pragma unroll
      for (int j = 0; j < 4; ++j) bfv[j] = *(const short8*)(Bs + (wn*64 + j*16 + l15)*64 + koff);
      #pragma unroll
      for (int i = 0; i < 4; ++i)
        #pragma unroll
        for (int j = 0; j < 4; ++j)
          acc[i][j] = __builtin_amdgcn_mfma_f32_16x16x32_bf16(af[i], bfv[j], acc[i][j], 0, 0, 0);
    }
    __syncthreads();
  }

  const int rbase = quad * 4;
  if (EPI == 0){
    #pragma unroll
    for (int i = 0; i < 4; ++i){
      int row = m0 + wm*64 + i*16 + rbase;
      #pragma unroll
      for (int j = 0; j < 4; ++j){
        int col = n0 + wn*64 + j*16 + l15;
        #pragma unroll
        for (int r = 0; r < 4; ++r)
          Cb[(size_t)(row + r)*1024 + col] = f2bf(acc[i][j][r]);
      }
    }
  } else {
    // LDS round-trip: 4 chunks of 32 rows; coalesced float4 epilogue
    float* cf = (float*)smem;
    const int lr = tid >> 3, seg = tid & 7;
    float4 lsv[4];
    #pragma unroll
    for (int k = 0; k < 4; ++k) lsv[k] = *(const float4*)(lsg + n0 + seg*16 + k*4);
    #pragma unroll
    for (int i = 0; i < 4; ++i){
      __syncthreads();
      #pragma unroll
      for (int j = 0; j < 4; ++j)
        #pragma unroll
        for (int r = 0; r < 4; ++r)
          cf[(wm*16 + rbase + r)*132 + wn*64 + j*16 + l15] = acc[i][j][r];
      __syncthreads();
      int grow = m0 + i*16 + (lr & 15) + (lr >> 4)*64;
      size_t gbase = (size_t)grow*1024 + n0 + seg*16;
      #pragma unroll
      for (int k = 0; k < 4; ++k){
        float4 o = *(const float4*)(cf + lr*132 + seg*16 + k*4);
        float4 xr = *(const float4*)(xres + gbase + k*4);
        float4 res;
        res.x = o.x*lsv[k].x + xr.x; res.y = o.y*lsv[k].y + xr.y;
        res.z = o.z*lsv[k].z + xr.z; res.w = o.w*lsv[k].w + xr.w;
        *(float4*)(Cf + gbase + k*4) = res;
      }
    }
  }
}

// fused Q/K/V/Gate GEMM: 1D grid 4096, m-major decode for A-tile L2 reuse
__global__ void gemm_qkvg(const u16* __restrict__ h, const u16* __restrict__ xb,
                          const u16* __restrict__ Wqb, const u16* __restrict__ Wkb,
                          const u16* __restrict__ Wvb, const u16* __restrict__ Wgb,
                          u16* __restrict__ Qb, u16* __restrict__ Kb,
                          u16* __restrict__ Vb, u16* __restrict__ Gb){
  int bid = blockIdx.x;
  int mblk = bid >> 5, sub = bid & 31;
  int sel = sub >> 3, nblk = sub & 7;
  const u16* A  = (sel == 3) ? xb : h;
  const u16* Bm = sel==0?Wqb : sel==1?Wkb : sel==2?Wvb : Wgb;
  u16* Out      = sel==0?Qb  : sel==1?Kb  : sel==2?Vb  : Gb;
  gemm_body<0>(A, Bm, Out, nullptr, nullptr, nullptr, mblk, nblk);
}

// y0 GEMM: 1D grid 1024, m-major decode
__global__ void gemm_y0(const u16* __restrict__ Kb, const u16* __restrict__ Wet,
                        u16* __restrict__ Yb){
  int bid = blockIdx.x;
  gemm_body<0>(Kb, Wet, Yb, nullptr, nullptr, nullptr, bid >> 3, bid & 7);
}

// final GEMM: 1D grid 1024, m-major decode; block 0 also writes loss output
__global__ void gemm_final(const u16* __restrict__ A, const u16* __restrict__ Bm,
                           float* __restrict__ C, const float* __restrict__ lsg,
                           const float* __restrict__ xres, const float* __restrict__ loss){
  int bid = blockIdx.x;
  if (bid == 0 && threadIdx.x == 0) C[16777216] = loss[0] * (1.0f/16777216.0f);
  gemm_body<1>(A, Bm, nullptr, C, lsg, xres, bid >> 3, bid & 7);
}

// ---- scan1: grad = K*(y0-V) -> Gr (bf16); per-chunk column sums; loss ------
// grid (4, 64, 4) = (cblock, chunk64, batch); 128 thr, 2 channels/thread
__global__ void scan1(const u16* __restrict__ Kb, const u16* __restrict__ Vb,
                      const u16* __restrict__ Yb, u16* __restrict__ Gr,
                      float* __restrict__ part, float* __restrict__ loss){
  int tid = threadIdx.x;               // 0..127
  int c2  = blockIdx.x*128 + tid;      // ushort2 index
  int ch = blockIdx.y, b = blockIdx.z;
  size_t base = ((size_t)b*4096 + (size_t)ch*64)*512 + c2;
  const ushort2* K2 = (const ushort2*)Kb;
  const ushort2* V2 = (const ushort2*)Vb;
  const ushort2* Y2 = (const ushort2*)Yb;
  ushort2* G2 = (ushort2*)Gr;
  float g0 = 0.f, g1 = 0.f, ls = 0.f;
  #pragma unroll 8
  for (int t = 0; t < 64; ++t){
    size_t idx = base + (size_t)t*512;
    ushort2 kv = K2[idx], vv = V2[idx], yv = Y2[idx];
    float e0 = bf2f(yv.x) - bf2f(vv.x);
    float e1 = bf2f(yv.y) - bf2f(vv.y);
    float gv0 = bf2f(kv.x)*e0, gv1 = bf2f(kv.y)*e1;
    ushort2 gw; gw.x = f2bf(gv0); gw.y = f2bf(gv1);
    G2[idx] = gw;
    g0 += gv0; g1 += gv1; ls += e0*e0 + e1*e1;
  }
  float2 pw; pw.x = g0; pw.y = g1;
  *(float2*)(part + ((size_t)(b*64 + ch))*1024 + c2*2) = pw;
  #pragma unroll
  for (int o = 32; o > 0; o >>= 1) ls += __shfl_down(ls, o);
  __shared__ float red[2];
  if ((tid & 63) == 0) red[tid >> 6] = ls;
  __syncthreads();
  if (tid == 0) atomicAdd(loss, red[0] + red[1]);
}

// -- scan2: out_pre = (y0 - Q*lr*shift*ps)*sigmoid(G), in place of Q ---------
// grid (4, 64, 4); 128 thr, 2 channels/thread
__global__ void scan2(const u16* __restrict__ Gr, const u16* __restrict__ Yb,
                      const u16* __restrict__ Qb, const u16* __restrict__ Gb,
                      const float* __restrict__ part, const float* __restrict__ lrc,
                      const float* __restrict__ psg, u16* __restrict__ OutPre){
  int tid = threadIdx.x;               // 0..127
  int c2  = blockIdx.x*128 + tid;
  int ch = blockIdx.y, b = blockIdx.z;
  __shared__ float ps_s[64];
  if (tid < 64) ps_s[tid] = psg[ch*64 + tid];
  int c = c2*2;
  float run0 = 0.f, run1 = 0.f;
  for (int j = 0; j < ch; ++j){
    float2 pp = *(const float2*)(part + ((size_t)(b*64 + j))*1024 + c);
    run0 += pp.x; run1 += pp.y;
  }
  float2 lr2 = *(const float2*)(lrc + c);
  __syncthreads();
  size_t base = ((size_t)b*4096 + (size_t)ch*64)*512 + c2;
  const ushort2* Gr2 = (const ushort2*)Gr;
  const ushort2* Yb2 = (const ushort2*)Yb;
  const ushort2* Qb2 = (const ushort2*)Qb;
  const ushort2* Gb2 = (const ushort2*)Gb;
  ushort2* Ot2 = (ushort2*)OutPre;
  #pragma unroll 8
  for (int t = 0; t < 64; ++t){
    size_t idx = base + (size_t)t*512;
    ushort2 gr = Gr2[idx], yv = Yb2[idx], qv = Qb2[idx], gl = Gb2[idx];
    float ps = ps_s[t];
    float g0 = 1.0f/(1.0f + expf(-bf2f(gl.x)));
    float g1 = 1.0f/(1.0f + expf(-bf2f(gl.y)));
    float o0 = (bf2f(yv.x) - bf2f(qv.x)*lr2.x*run0*ps) * g0;
    float o1 = (bf2f(yv.y) - bf2f(qv.y)*lr2.y*run1*ps) * g1;
    ushort2 ov; ov.x = f2bf(o0); ov.y = f2bf(o1);
    Ot2[idx] = ov;                    // same buffer as Qb: read-before-write
    run0 += bf2f(gr.x); run1 += bf2f(gr.y);
  }
}

extern "C" void kernel_launch(void* const* d_in, const int* in_sizes, int n_in,
                              void* d_out, int out_size, void* d_ws, size_t ws_size,
                              hipStream_t stream){
  const float* x   = (const float*)d_in[0];
  const float* W0  = (const float*)d_in[1];
  const float* Ai  = (const float*)d_in[2];
  const float* Bi  = (const float*)d_in[3];
  const float* llr = (const float*)d_in[4];
  const float* Wq  = (const float*)d_in[5];
  const float* Wk  = (const float*)d_in[6];
  const float* Wv  = (const float*)d_in[7];
  const float* Wo  = (const float*)d_in[8];
  const float* Wg  = (const float*)d_in[9];
  const float* lng = (const float*)d_in[10];
  const float* lnb = (const float*)d_in[11];
  const float* lsg = (const float*)d_in[12];
  float* out = (float*)d_out;

  const size_t TOK = 16384, CC = 1024;
  char* p = (char*)d_ws;
  float* loss = (float*)p; p += 256;
  u16* h   = (u16*)p; p += TOK*CC*2;   // LN out; reused as y0 after gemm_y0
  u16* xb  = (u16*)p; p += TOK*CC*2;   // x bf16; reused as Gr after qkvg
  u16* Qb  = (u16*)p; p += TOK*CC*2;   // becomes out_pre in scan2
  u16* Kb  = (u16*)p; p += TOK*CC*2;
  u16* Vb  = (u16*)p; p += TOK*CC*2;
  u16* Gb  = (u16*)p; p += TOK*CC*2;
  u16* Wqb = (u16*)p; p += CC*CC*2;
  u16* Wkb = (u16*)p; p += CC*CC*2;
  u16* Wvb = (u16*)p; p += CC*CC*2;
  u16* Wgb = (u16*)p; p += CC*CC*2;
  u16* Wob = (u16*)p; p += CC*CC*2;
  u16* Wet = (u16*)p; p += CC*CC*2;
  float* psg  = (float*)p; p += 4096*4;
  float* lrc  = (float*)p; p += 1024*4;
  float* part = (float*)p; p += (size_t)256*1024*4;

  prep_all<<<22544, 256, 0, stream>>>(x, lng, lnb, Wq, Wk, Wv, Wg, Wo, W0, Ai, Bi, llr,
                                      h, xb, Wqb, Wkb, Wvb, Wgb, Wob, Wet, psg, lrc, loss);
  gemm_qkvg<<<4096, 256, 0, stream>>>(h, xb, Wqb, Wkb, Wvb, Wgb, Qb, Kb, Vb, Gb);
  gemm_y0<<<1024, 256, 0, stream>>>(Kb, Wet, h);
  scan1<<<dim3(4, 64, 4), 128, 0, stream>>>(Kb, Vb, h, xb, part, loss);
  scan2<<<dim3(4, 64, 4), 128, 0, stream>>>(xb, h, Qb, Gb, part, lrc, psg, Qb);
  gemm_final<<<1024, 256, 0, stream>>>(Qb, Wob, out, lsg, x, loss);
}